// Round 2
// baseline (593.224 us; speedup 1.0000x reference)
//
#include <hip/hip_runtime.h>
#include <math.h>

// Problem constants (fixed by the reference)
constexpr int kT = 500000;     // history length
constexpr int kQ = 256;        // feature size
constexpr int kH = 256;        // hidden size
constexpr int kK = 32;         // attn_k
constexpr int kNB1 = 256;      // phase-1 top-k blocks
constexpr int kCHUNK = (kT + kNB1 - 1) / kNB1;  // 1954
constexpr int kNC = kNB1 * kK; // 8192 merge candidates
constexpr int kGruRows = 3 * kH;              // 768
constexpr int kGruBlocks = kGruRows / 4;      // 192 (4 waves/block, 1 row/wave)

typedef float f4  __attribute__((ext_vector_type(4)));
// 16B vector with 4B alignment: compiles to global_store_dwordx4 (ISA multi-
// dword ops only need dword alignment) — the out region is +1 float offset.
typedef float f4u __attribute__((ext_vector_type(4), aligned(4)));

// Scratch requirement (floats): alpha kT + candV kNC + candI kNC + gi/gh 2*768
constexpr size_t kScratchFloats = (size_t)kT + 2 * kNC + 2 * kGruRows;

// ---------------------------------------------------------------------------
// Big fused copy: qs -> qs_new rows [0,kT] (row kT = ques_h append) computing
// alpha = qs @ ques_h on the fly; optionally hs -> hs_new rows [0,kT).
// One wave per row; lane l owns float4 [4l..4l+3].
__global__ __launch_bounds__(256) void k_bigcopy(
    const float* __restrict__ qs, const float* __restrict__ hs,
    const float* __restrict__ qh, float* __restrict__ out,
    float* __restrict__ alpha, int doHs) {
  const int lane = threadIdx.x & 63;
  const int wid  = (int)((blockIdx.x * blockDim.x + threadIdx.x) >> 6);
  const int nw   = (int)((gridDim.x * blockDim.x) >> 6);
  const f4 q4 = ((const f4*)qh)[lane];
  const int totalRows = doHs ? (2 * kT + 1) : (kT + 1);
  for (int t = wid; t < totalRows; t += nw) {
    if (t <= kT) {
      const f4* src = (t < kT) ? (const f4*)(qs + (size_t)t * kQ)
                               : (const f4*)qh;
      f4 v = src[lane];
      *(f4u*)(out + 1 + (size_t)t * kQ + lane * 4) = v;
      if (t < kT) {
        float d = v.x * q4.x + v.y * q4.y + v.z * q4.z + v.w * q4.w;
#pragma unroll
        for (int off = 32; off; off >>= 1) d += __shfl_xor(d, off);
        if (lane == 0) alpha[t] = d;
      }
    } else {
      const int r = t - (kT + 1);
      f4 v = ((const f4*)(hs + (size_t)r * kH))[lane];
      *(f4u*)(out + 1 + (size_t)(kT + 1) * kQ + (size_t)r * kH + lane * 4) = v;
    }
  }
}

// Standalone hs copy for the fallback (scratch-in-output) path; runs LAST.
__global__ __launch_bounds__(256) void k_copy_hs(
    const float* __restrict__ hs, float* __restrict__ out) {
  const size_t i      = (size_t)blockIdx.x * blockDim.x + threadIdx.x;
  const size_t stride = (size_t)gridDim.x * blockDim.x;
  float* base = out + 1 + (size_t)(kT + 1) * kQ;
  const f4* src = (const f4*)hs;
  const size_t nv = (size_t)kT * (kH / 4);
  for (size_t v = i; v < nv; v += stride) {
    *(f4u*)(base + v * 4) = src[v];
  }
}

// ---------------------------------------------------------------------------
// Fused: blocks [0,kNB1) do per-chunk top-32 of alpha; blocks [kNB1, +192) do
// the GRU matvecs (1 row per wave, 4 waves/block).
__global__ __launch_bounds__(256) void k_topk_gru(
    const float* __restrict__ alpha, float* __restrict__ candV,
    int* __restrict__ candI,
    const float* __restrict__ Wih, const float* __restrict__ Whh,
    const float* __restrict__ bih, const float* __restrict__ bhh,
    const float* __restrict__ qh, const float* __restrict__ hs,
    const float* __restrict__ score, float* __restrict__ gi,
    float* __restrict__ gh) {
  const int tid = threadIdx.x;
  if (blockIdx.x >= kNB1) {
    // ---- GRU matvec part ----
    const int lane = tid & 63;
    const int r = (blockIdx.x - kNB1) * 4 + (tid >> 6);
    const int off = (score[0] >= 0.5f) ? 0 : kQ;  // x = [qh*ge, qh*(1-ge)]
    const float* hprev = hs + (size_t)(kT - 1) * kH;
    f4 q4 = ((const f4*)qh)[lane];
    f4 h4 = ((const f4*)hprev)[lane];
    f4 wi = ((const f4*)(Wih + (size_t)r * (2 * kQ) + off))[lane];
    f4 wh = ((const f4*)(Whh + (size_t)r * kH))[lane];
    float di = wi.x * q4.x + wi.y * q4.y + wi.z * q4.z + wi.w * q4.w;
    float dh = wh.x * h4.x + wh.y * h4.y + wh.z * h4.z + wh.w * h4.w;
#pragma unroll
    for (int o = 32; o; o >>= 1) {
      di += __shfl_xor(di, o);
      dh += __shfl_xor(dh, o);
    }
    if (lane == 0) {
      gi[r] = di + bih[r];
      gh[r] = dh + bhh[r];
    }
    return;
  }
  // ---- top-k phase 1 part ----
  __shared__ float sv[kCHUNK];
  __shared__ float rv[4];
  __shared__ int ri[4];
  const int base = blockIdx.x * kCHUNK;
  for (int i = tid; i < kCHUNK; i += 256) {
    int g = base + i;
    sv[i] = (g < kT) ? alpha[g] : -INFINITY;
  }
  __syncthreads();
  for (int k = 0; k < kK; ++k) {
    float bv = -INFINITY; int bi = -1;
    for (int i = tid; i < kCHUNK; i += 256) {
      float v = sv[i];
      if (v > bv) { bv = v; bi = i; }
    }
#pragma unroll
    for (int off = 32; off; off >>= 1) {
      float ov = __shfl_xor(bv, off);
      int   oi = __shfl_xor(bi, off);
      if (ov > bv || (ov == bv && oi != -1 && (bi == -1 || oi < bi))) { bv = ov; bi = oi; }
    }
    if ((tid & 63) == 0) { rv[tid >> 6] = bv; ri[tid >> 6] = bi; }
    __syncthreads();
    if (tid == 0) {
      float fv = rv[0]; int fi = ri[0];
      for (int j = 1; j < 4; ++j)
        if (rv[j] > fv || (rv[j] == fv && ri[j] != -1 && (fi == -1 || ri[j] < fi))) {
          fv = rv[j]; fi = ri[j];
        }
      candV[blockIdx.x * kK + k] = fv;
      candI[blockIdx.x * kK + k] = (fi >= 0) ? (base + fi) : 0;
      if (fi >= 0) sv[fi] = -INFINITY;
    }
    __syncthreads();
  }
}

// ---------------------------------------------------------------------------
// Fused: block 0 = candidate merge + softmax + attn + pred; block 1 = GRU
// gates + write hs_new row kT.
__global__ __launch_bounds__(256) void k_attn_gru2(
    const float* __restrict__ candV, const int* __restrict__ candI,
    const float* __restrict__ hs, const float* __restrict__ qh,
    const float* __restrict__ Ws, const float* __restrict__ bs,
    const float* __restrict__ gi, const float* __restrict__ gh,
    float* __restrict__ out) {
  const int tid = threadIdx.x;
  if (blockIdx.x == 1) {
    // ---- GRU gates ----
    const float* hprev = hs + (size_t)(kT - 1) * kH;
    float rr = 1.f / (1.f + expf(-(gi[tid] + gh[tid])));
    float z  = 1.f / (1.f + expf(-(gi[kH + tid] + gh[kH + tid])));
    float n  = tanhf(gi[2 * kH + tid] + rr * gh[2 * kH + tid]);
    float hn = (1.f - z) * n + z * hprev[tid];
    out[1 + (size_t)(kT + 1) * kQ + (size_t)kT * kH + tid] = hn;
    return;
  }
  __shared__ float sv[kNC];
  __shared__ float rv[4];
  __shared__ int ri[4];
  __shared__ float topv[kK];
  __shared__ int topi[kK];
  __shared__ float w[kK];
  __shared__ float red[256];
  for (int i = tid; i < kNC; i += 256) sv[i] = candV[i];
  __syncthreads();
  for (int k = 0; k < kK; ++k) {
    float bv = -INFINITY; int bi = -1;
    for (int i = tid; i < kNC; i += 256) {
      float v = sv[i];
      if (v > bv) { bv = v; bi = i; }
    }
#pragma unroll
    for (int off = 32; off; off >>= 1) {
      float ov = __shfl_xor(bv, off);
      int   oi = __shfl_xor(bi, off);
      if (ov > bv || (ov == bv && oi != -1 && (bi == -1 || oi < bi))) { bv = ov; bi = oi; }
    }
    if ((tid & 63) == 0) { rv[tid >> 6] = bv; ri[tid >> 6] = bi; }
    __syncthreads();
    if (tid == 0) {
      float fv = rv[0]; int fi = ri[0];
      for (int j = 1; j < 4; ++j)
        if (rv[j] > fv || (rv[j] == fv && ri[j] != -1 && (fi == -1 || ri[j] < fi))) {
          fv = rv[j]; fi = ri[j];
        }
      topv[k] = fv;
      topi[k] = candI[fi];
      sv[fi] = -INFINITY;
    }
    __syncthreads();
  }
  if (tid == 0) {
    float m = topv[0];
    for (int j = 1; j < kK; ++j) m = fmaxf(m, topv[j]);
    float s = 0.f;
    for (int j = 0; j < kK; ++j) { w[j] = expf(topv[j] - m); s += w[j]; }
    float inv = 1.f / s;
    for (int j = 0; j < kK; ++j) w[j] *= inv;
  }
  __syncthreads();
  float a = 0.f;
#pragma unroll
  for (int j = 0; j < kK; ++j) a += w[j] * hs[(size_t)topi[j] * kH + tid];
  red[tid] = Ws[tid] * qh[tid] + Ws[kQ + tid] * a;
  __syncthreads();
  for (int s = 128; s; s >>= 1) {
    if (tid < s) red[tid] += red[tid + s];
    __syncthreads();
  }
  if (tid == 0) out[0] = red[0] + bs[0];
}

extern "C" void kernel_launch(void* const* d_in, const int* in_sizes, int n_in,
                              void* d_out, int out_size, void* d_ws, size_t ws_size,
                              hipStream_t stream) {
  const float* qh    = (const float*)d_in[0];
  const float* score = (const float*)d_in[1];
  const float* qs    = (const float*)d_in[2];
  const float* hs    = (const float*)d_in[3];
  const float* Wih   = (const float*)d_in[4];
  const float* Whh   = (const float*)d_in[5];
  const float* bih   = (const float*)d_in[6];
  const float* bhh   = (const float*)d_in[7];
  const float* Ws    = (const float*)d_in[8];
  const float* bs    = (const float*)d_in[9];
  float* out = (float*)d_out;

  const bool useWs = ws_size >= kScratchFloats * sizeof(float);
  // Fallback: scratch lives at the start of the hs_new output region and is
  // consumed before the final hs copy overwrites it.
  float* S = useWs ? (float*)d_ws : (out + 1 + (size_t)(kT + 1) * kQ);
  float* alpha = S;                      // kT floats
  float* candV = S + kT;                 // kNC floats
  int*   candI = (int*)(S + kT + kNC);   // kNC ints
  float* gi    = S + kT + 2 * kNC;       // 768 floats
  float* gh    = gi + kGruRows;          // 768 floats

  if (useWs) {
    // One big dispatch covers both copies + alpha.
    hipLaunchKernelGGL(k_bigcopy, dim3(2048), dim3(256), 0, stream,
                       qs, hs, qh, out, alpha, 1);
    hipLaunchKernelGGL(k_topk_gru, dim3(kNB1 + kGruBlocks), dim3(256), 0, stream,
                       alpha, candV, candI, Wih, Whh, bih, bhh, qh, hs, score,
                       gi, gh);
    hipLaunchKernelGGL(k_attn_gru2, dim3(2), dim3(256), 0, stream,
                       candV, candI, hs, qh, Ws, bs, gi, gh, out);
  } else {
    hipLaunchKernelGGL(k_bigcopy, dim3(2048), dim3(256), 0, stream,
                       qs, hs, qh, out, alpha, 0);
    hipLaunchKernelGGL(k_topk_gru, dim3(kNB1 + kGruBlocks), dim3(256), 0, stream,
                       alpha, candV, candI, Wih, Whh, bih, bhh, qh, hs, score,
                       gi, gh);
    hipLaunchKernelGGL(k_attn_gru2, dim3(2), dim3(256), 0, stream,
                       candV, candI, hs, qh, Ws, bs, gi, gh, out);
    hipLaunchKernelGGL(k_copy_hs, dim3(2048), dim3(256), 0, stream,
                       hs, out);
  }
}